// Round 18
// baseline (150.192 us; speedup 1.0000x reference)
//
#include <hip/hip_runtime.h>

#define HWZ 32768   // 64*64*8 spatial positions
#define NH 8

typedef __bf16 bf16x8 __attribute__((ext_vector_type(8)));
typedef unsigned short u16x8 __attribute__((ext_vector_type(8)));
typedef unsigned short u16x4 __attribute__((ext_vector_type(4)));
typedef short s16x4 __attribute__((ext_vector_type(4)));
typedef float f32x4 __attribute__((ext_vector_type(4)));

// ws layout (float offsets):
// [Spart 128x4 (0..511) | SSpart (512..1023) | sync counters (1024..1031)]
// bf16 QKV @2048 | bf16 w_proj^T | bf16 w_qkv^T
// Q: [head][p][d]   K: [head][p][d]   V: [head][d][p]  (transposed!)
#define SYNC_F_OFF 1024
#define QKV_F_OFF 2048
#define HEADSZ (HWZ * 16)                        // ushorts per head
#define REGSZ  (NH * HEADSZ)                     // ushorts per tensor (q/k/v)
#define WT_F_OFF  (QKV_F_OFF + (3 * REGSZ) / 2)  // w_proj^T: 128x128 u16
#define WQT_F_OFF (WT_F_OFF + 8192)              // w_qkv^T: 384x128 u16

__device__ __forceinline__ unsigned short f2bf(float f) {
    unsigned int u = __builtin_bit_cast(unsigned int, f);
    unsigned int r = u + 0x7FFFu + ((u >> 16) & 1u);   // RNE
    return (unsigned short)(r >> 16);
}

// device-scope sense barrier: grid (512 blocks) is guaranteed co-resident at
// __launch_bounds__(512,4) + 16KB LDS -> 2 blocks/CU x 256 CUs, so no deadlock.
__device__ __forceinline__ void grid_barrier(int* cnt, int* flag, int nblocks) {
    __syncthreads();
    if (threadIdx.x == 0) {
        __threadfence();                       // release: all our writes visible (agent scope)
        int old = atomicAdd(cnt, 1);           // device-scope by default
        if (old == nblocks - 1) {
            __hip_atomic_store(flag, 1, __ATOMIC_RELEASE, __HIP_MEMORY_SCOPE_AGENT);
        } else {
            while (__hip_atomic_load(flag, __ATOMIC_ACQUIRE, __HIP_MEMORY_SCOPE_AGENT) == 0) {
                __builtin_amdgcn_s_sleep(2);
            }
        }
        __threadfence();                       // acquire: invalidate L1/L2 stale lines
    }
    __syncthreads();
}

__global__ __launch_bounds__(512, 4) void mega_kernel(
        const float* __restrict__ x,      const float* __restrict__ w_qkv,
        const float* __restrict__ b_qkv,  const float* __restrict__ rpb,
        const float* __restrict__ w_proj, const float* __restrict__ b_proj,
        float* __restrict__ ws,           float* __restrict__ out) {
    __shared__ alignas(16) unsigned char smem[16384];   // union across phases
    const int tid = threadIdx.x;
    const int bid = blockIdx.x;        // 512 blocks
    int* sync = (int*)(ws + SYNC_F_OFF);   // [cnt0, flag0, cnt1, flag1], memset to 0 pre-launch

    // ============ phase 0: weight transpose + per-channel stats partials ============
    {
        if (tid < 128) {
            if (bid < 384) {
                unsigned short* wqt = (unsigned short*)(ws + WQT_F_OFF);
                wqt[bid * 128 + tid] = f2bf(w_qkv[(size_t)tid * 384 + bid]);
            } else {
                int j = bid - 384;
                unsigned short* wpt = (unsigned short*)(ws + WT_F_OFF);
                wpt[j * 128 + tid] = f2bf(w_proj[(size_t)tid * 128 + j]);
            }
        }
        int c = bid >> 2, qtr = bid & 3;   // 4 blocks/channel, fixed partition (deterministic)
        const float4* xp = (const float4*)(x + (size_t)c * HWZ + qtr * 8192);
        float s = 0.f, ss = 0.f;
#pragma unroll
        for (int i = 0; i < 4; i++) {
            float4 v = xp[tid + i * 512];
            s  += v.x + v.y + v.z + v.w;
            ss += v.x*v.x + v.y*v.y + v.z*v.z + v.w*v.w;
        }
        for (int off = 32; off; off >>= 1) {
            s  += __shfl_down(s, off);
            ss += __shfl_down(ss, off);
        }
        float* red = (float*)smem;
        int lane = tid & 63, wid = tid >> 6;
        if (lane == 0) { red[wid] = s; red[8 + wid] = ss; }
        __syncthreads();
        if (tid == 0) {
            float S = 0.f, SS = 0.f;
            for (int w = 0; w < 8; w++) { S += red[w]; SS += red[8 + w]; }
            ws[c * 4 + qtr] = S;
            ws[512 + c * 4 + qtr] = SS;
        }
    }
    grid_barrier(&sync[0], &sync[1], 512);

    // ============ phase 1: QKV GEMM via bf16 MFMA (partials reduced inline) ============
    {
        unsigned short* xs = (unsigned short*)smem;   // [p][c] bf16, swizzled by p&15
        const int p0 = bid * 64;
        {
            const int pgrp = tid & 15;        // p = pgrp*4 .. +3
            const int c0   = (tid >> 4) * 4;  // c = c0 .. c0+3
            float mus[4], rss[4];
#pragma unroll
            for (int ci = 0; ci < 4; ci++) {
                float4 sp = *(const float4*)(ws + (c0 + ci) * 4);
                float4 sq = *(const float4*)(ws + 512 + (c0 + ci) * 4);
                float S  = sp.x + sp.y + sp.z + sp.w;
                float SS = sq.x + sq.y + sq.z + sq.w;
                float mu = S * (1.0f / HWZ);
                float var = SS * (1.0f / HWZ) - mu * mu;
                mus[ci] = mu;
                rss[ci] = rsqrtf(var + 1e-5f);
            }
            unsigned short vals[4][4];        // [ci][pi]
#pragma unroll
            for (int ci = 0; ci < 4; ci++) {
                float4 v = *(const float4*)(x + (size_t)(c0 + ci) * HWZ + p0 + pgrp * 4);
                vals[ci][0] = f2bf((v.x - mus[ci]) * rss[ci]);
                vals[ci][1] = f2bf((v.y - mus[ci]) * rss[ci]);
                vals[ci][2] = f2bf((v.z - mus[ci]) * rss[ci]);
                vals[ci][3] = f2bf((v.w - mus[ci]) * rss[ci]);
            }
            const int c8 = c0 >> 3, cl = c0 & 7;
#pragma unroll
            for (int pi = 0; pi < 4; pi++) {
                int p = pgrp * 4 + pi;
                u16x4 o = {vals[0][pi], vals[1][pi], vals[2][pi], vals[3][pi]};
                *(u16x4*)(xs + p * 128 + ((c8 ^ (p & 15)) << 3) + cl) = o;
            }
        }
        __syncthreads();

        const int wv   = tid >> 6;
        const int lane = tid & 63;
        const int col  = lane & 15;
        const int kgrp = lane >> 4;
        const int ptile = wv & 3;
        const int jq    = wv >> 2;
        const unsigned short* arow = xs + (ptile * 16 + col) * 128;
        const int arow15 = (ptile * 16 + col) & 15;

        u16x8 a[4];
#pragma unroll
        for (int ks = 0; ks < 4; ks++) {
            a[ks] = *(const u16x8*)(arow + (((ks * 4 + kgrp) ^ arow15) << 3));
        }
        __syncthreads();   // fragment reads done -> xs front reusable as transpose scratch

        const unsigned short* wqt = (const unsigned short*)(ws + WQT_F_OFF);
        unsigned short* qkvb = (unsigned short*)(ws + QKV_F_OFF);
        unsigned short* vsc = xs + wv * 320;            // wave-private, stride-20 rows
        const int rp_ = lane & 15, rdseg = lane >> 4;

        for (int chunk = 0; chunk < 3; chunk++) {
            float scale = (chunk == 0) ? 0.25f : 1.0f;
#pragma unroll
            for (int jt = 0; jt < 4; jt++) {
                int jl = jq * 64 + jt * 16 + col;
                const unsigned short* brow = wqt + (size_t)(chunk * 128 + jl) * 128;
                f32x4 acc = {0.f, 0.f, 0.f, 0.f};
#pragma unroll
                for (int ks = 0; ks < 4; ks++) {
                    u16x8 b = *(const u16x8*)(brow + ((ks * 4 + kgrp) << 3));
                    acc = __builtin_amdgcn_mfma_f32_16x16x32_bf16(
                            __builtin_bit_cast(bf16x8, a[ks]),
                            __builtin_bit_cast(bf16x8, b), acc, 0, 0, 0);
                }
                int head = jq * 4 + jt;
                float bias = b_qkv[chunk * 128 + head * 16 + col];
                if (chunk == 2) {
                    unsigned short* vt = qkvb + 2 * (size_t)REGSZ
                                       + ((size_t)(head * 16 + col)) * HWZ
                                       + p0 + ptile * 16 + kgrp * 4;
                    u16x4 o;
#pragma unroll
                    for (int i = 0; i < 4; i++) o[i] = f2bf(acc[i] + bias);
                    *(u16x4*)vt = o;
                } else {
#pragma unroll
                    for (int i = 0; i < 4; i++) {
                        vsc[(kgrp * 4 + i) * 20 + col] = f2bf((acc[i] + bias) * scale);
                    }
                    asm volatile("s_waitcnt lgkmcnt(0)" ::: "memory");
                    u16x4 vv = *(const u16x4*)(vsc + rp_ * 20 + rdseg * 4);
                    unsigned short* dst = qkvb + (size_t)chunk * REGSZ + (size_t)head * HEADSZ
                                        + (size_t)(p0 + ptile * 16 + rp_) * 16 + rdseg * 4;
                    *(u16x4*)dst = vv;
                }
            }
        }
    }
    grid_barrier(&sync[2], &sync[3], 512);

    // ============ phase 2: fused NATTEN attention + proj (2 tasks/block) ============
    {
        unsigned short* aol = (unsigned short*)smem;        // 8 KB
        float* rpb_s = (float*)(smem + 8192);               // 4 KB
        for (int i = tid; i < 1024; i += 512) {
            int hh = i >> 7, e = i & 127;
            rpb_s[i] = (e < 125) ? rpb[hh * 125 + e] : 0.f;
        }
        __syncthreads();

        const int wv = tid >> 6, lane = tid & 63;
        const int head = wv;
        const int g = lane >> 4;
        const int qcol = lane & 15;
        const int lw = qcol >> 3, qz = qcol & 7;
        const int z = qz;
        const int sz = min(max(z - 1, 0), 5);
        unsigned zmask = 0;
#pragma unroll
        for (int zp = 0; zp < 8; zp++) {
            if (zp >= sz && zp <= sz + 2) zmask |= 1u << zp;
        }

        const unsigned short* qkvb = (const unsigned short*)(ws + QKV_F_OFF);
        const unsigned short* qbase = qkvb + (size_t)head * HEADSZ;
        const unsigned short* kbase = qkvb + (size_t)REGSZ + (size_t)head * HEADSZ;
        const unsigned short* vtb  = qkvb + 2 * (size_t)REGSZ + (size_t)(head * 16) * HWZ;
        const float* bt = rpb_s + head * 128;
        const unsigned short* wpt = (const unsigned short*)(ws + WT_F_OFF);
        const int j = wv * 16 + qcol;

        const int iwlA = qcol >> 3, zpA = qcol & 7;
        const int iwlV = g >> 1,   zp0V = (g & 1) * 4;

#pragma unroll 1
        for (int it = 0; it < 2; it++) {
            const int blk = (bid & 7) * 128 + (bid >> 3) * 2 + it;   // XCD-aware, bijective
            const int p0 = blk * 32;
            const int h0 = p0 >> 9;
            const int w0 = (p0 >> 3) & 63;
            const int sh = min(max(h0 - 1, 0), 61);
            const int dh = sh - h0 + 2;

#pragma unroll 1
            for (int t = 0; t < 2; t++) {
                const int pt = p0 + t * 16;
                const int w0t = w0 + t * 2;
                const int w = w0t + lw;
                const int sw = min(max(w - 1, 0), 61);
                unsigned wmask = 0;
#pragma unroll
                for (int iw = 0; iw < 4; iw++) {
                    int W = w0t - 1 + iw;
                    if (W >= sw && W <= sw + 2) wmask |= 1u << iw;
                }
                int Wc[4];
#pragma unroll
                for (int iw = 0; iw < 4; iw++) Wc[iw] = min(max(w0t - 1 + iw, 0), 63);

                s16x4 bq = *(const s16x4*)(qbase + (size_t)(pt + qcol) * 16 + g * 4);
                s16x4 ak[6], av[6];
#pragma unroll
                for (int mt = 0; mt < 6; mt++) {
                    int iwA = (mt & 1) * 2 + iwlA;
                    int pkK = (sh + (mt >> 1)) * 512 + Wc[iwA] * 8 + zpA;
                    ak[mt] = *(const s16x4*)(kbase + (size_t)pkK * 16 + g * 4);
                    int iwV = (mt & 1) * 2 + iwlV;
                    int pkV = (sh + (mt >> 1)) * 512 + Wc[iwV] * 8 + zp0V;
                    av[mt] = *(const s16x4*)(vtb + (size_t)qcol * HWZ + pkV);
                }

                f32x4 acc[6];
#pragma unroll
                for (int mt = 0; mt < 6; mt++) {
                    f32x4 zero = {0.f, 0.f, 0.f, 0.f};
                    acc[mt] = __builtin_amdgcn_mfma_f32_16x16x16bf16_1k(ak[mt], bq, zero, 0, 0, 0);
                }

                float ssum = 0.f;
#pragma unroll
                for (int mt = 0; mt < 6; mt++) {
                    int ih = mt >> 1;
#pragma unroll
                    for (int r = 0; r < 4; r++) {
                        int krow = g * 4 + r;
                        int iw = (mt & 1) * 2 + (krow >> 3);
                        int zp = krow & 7;
                        int ok = ((wmask >> iw) & 1) & ((zmask >> zp) & 1);
                        int idx = (dh + ih) * 25 + (iw + 1 - lw) * 5 + (zp - z + 2);
                        idx = ok ? idx : 62;
                        float lg = ok ? (acc[mt][r] + bt[idx]) : -1e30f;
                        float pexp = __expf(lg);
                        acc[mt][r] = pexp;
                        ssum += pexp;
                    }
                }
                ssum += __shfl_xor(ssum, 16);
                ssum += __shfl_xor(ssum, 32);
                float inv = 1.f / ssum;

                s16x4 pb[6];
#pragma unroll
                for (int mt = 0; mt < 6; mt++)
#pragma unroll
                    for (int r = 0; r < 4; r++)
                        pb[mt][r] = (short)f2bf(acc[mt][r]);

                f32x4 o0 = {0.f, 0.f, 0.f, 0.f}, o1 = {0.f, 0.f, 0.f, 0.f};
                o0 = __builtin_amdgcn_mfma_f32_16x16x16bf16_1k(av[0], pb[0], o0, 0, 0, 0);
                o1 = __builtin_amdgcn_mfma_f32_16x16x16bf16_1k(av[1], pb[1], o1, 0, 0, 0);
                o0 = __builtin_amdgcn_mfma_f32_16x16x16bf16_1k(av[2], pb[2], o0, 0, 0, 0);
                o1 = __builtin_amdgcn_mfma_f32_16x16x16bf16_1k(av[3], pb[3], o1, 0, 0, 0);
                o0 = __builtin_amdgcn_mfma_f32_16x16x16bf16_1k(av[4], pb[4], o0, 0, 0, 0);
                o1 = __builtin_amdgcn_mfma_f32_16x16x16bf16_1k(av[5], pb[5], o1, 0, 0, 0);
                f32x4 oacc = o0 + o1;

#pragma unroll
                for (int r = 0; r < 4; r++) {
                    int c = head * 16 + g * 4 + r;
                    aol[(t * 16 + qcol) * 128 + (((c >> 3) ^ qcol) << 3) + (c & 7)] = f2bf(oacc[r] * inv);
                }
            }

            // proj B-fragments before the barrier (independent of aol)
            const unsigned short* bp = wpt + j * 128;
            u16x8 b0 = *(const u16x8*)(bp + ((0 * 4 + g) << 3));
            u16x8 b1 = *(const u16x8*)(bp + ((1 * 4 + g) << 3));
            u16x8 b2 = *(const u16x8*)(bp + ((2 * 4 + g) << 3));
            u16x8 b3 = *(const u16x8*)(bp + ((3 * 4 + g) << 3));
            float bias = b_proj[j];
            __syncthreads();

#pragma unroll
            for (int t = 0; t < 2; t++) {
                const unsigned short* ap = aol + (t * 16 + qcol) * 128;
                u16x8 a[4];
#pragma unroll
                for (int ks = 0; ks < 4; ks++) {
                    a[ks] = *(const u16x8*)(ap + (((ks * 4 + g) ^ qcol) << 3));
                }
                f32x4 p0a = {0.f, 0.f, 0.f, 0.f}, p1a = {0.f, 0.f, 0.f, 0.f};
                p0a = __builtin_amdgcn_mfma_f32_16x16x32_bf16(__builtin_bit_cast(bf16x8, a[0]),
                        __builtin_bit_cast(bf16x8, b0), p0a, 0, 0, 0);
                p1a = __builtin_amdgcn_mfma_f32_16x16x32_bf16(__builtin_bit_cast(bf16x8, a[1]),
                        __builtin_bit_cast(bf16x8, b1), p1a, 0, 0, 0);
                p0a = __builtin_amdgcn_mfma_f32_16x16x32_bf16(__builtin_bit_cast(bf16x8, a[2]),
                        __builtin_bit_cast(bf16x8, b2), p0a, 0, 0, 0);
                p1a = __builtin_amdgcn_mfma_f32_16x16x32_bf16(__builtin_bit_cast(bf16x8, a[3]),
                        __builtin_bit_cast(bf16x8, b3), p1a, 0, 0, 0);
                f32x4 pacc = p0a + p1a;

                float4 o4;
                o4.x = pacc[0] + bias; o4.y = pacc[1] + bias;
                o4.z = pacc[2] + bias; o4.w = pacc[3] + bias;
                *(float4*)(out + (size_t)j * HWZ + p0 + t * 16 + g * 4) = o4;
            }
            __syncthreads();   // aol consumed before next task overwrites
        }
    }
}

extern "C" void kernel_launch(void* const* d_in, const int* in_sizes, int n_in,
                              void* d_out, int out_size, void* d_ws, size_t ws_size,
                              hipStream_t stream) {
    const float* x      = (const float*)d_in[0];
    const float* w_qkv  = (const float*)d_in[1];
    const float* b_qkv  = (const float*)d_in[2];
    const float* rpb    = (const float*)d_in[3];
    const float* w_proj = (const float*)d_in[4];
    const float* b_proj = (const float*)d_in[5];
    float* out = (float*)d_out;
    float* ws  = (float*)d_ws;

    // zero the 4 sync ints (cnt0, flag0, cnt1, flag1) -- capture-safe async memset
    hipMemsetAsync((void*)(ws + SYNC_F_OFF), 0, 16, stream);
    mega_kernel<<<512, 512, 0, stream>>>(x, w_qkv, b_qkv, rpb, w_proj, b_proj, ws, out);
}

// Round 19
// 60.654 us; speedup vs baseline: 2.4762x; 2.4762x over previous
//
#include <hip/hip_runtime.h>

#define HWZ 32768   // 64*64*8 spatial positions
#define NH 8

typedef __bf16 bf16x8 __attribute__((ext_vector_type(8)));
typedef unsigned short u16x8 __attribute__((ext_vector_type(8)));
typedef unsigned short u16x4 __attribute__((ext_vector_type(4)));
typedef short s16x4 __attribute__((ext_vector_type(4)));
typedef float f32x4 __attribute__((ext_vector_type(4)));

// ws layout (float offsets):
// [Spart 128x4 (0..511) | SSpart (512..1023)] | bf16 QKV | bf16 w_proj^T | bf16 w_qkv^T
// Q: [head][p][d]   K: [head][p][d]   V: [head][d][p]  (transposed!)
#define QKV_F_OFF 1024
#define HEADSZ (HWZ * 16)                        // ushorts per head
#define REGSZ  (NH * HEADSZ)                     // ushorts per tensor (q/k/v)
#define WT_F_OFF  (QKV_F_OFF + (3 * REGSZ) / 2)  // w_proj^T: 128x128 u16
#define WQT_F_OFF (WT_F_OFF + 8192)              // w_qkv^T: 384x128 u16

__device__ __forceinline__ unsigned short f2bf(float f) {
    unsigned int u = __builtin_bit_cast(unsigned int, f);
    unsigned int r = u + 0x7FFFu + ((u >> 16) & 1u);   // RNE
    return (unsigned short)(r >> 16);
}

// ---------------- prep: full-GPU stats partials (4 blocks/channel) + weight transpose ----------------
__global__ __launch_bounds__(512) void prep_kernel(const float* __restrict__ x,
                                                   const float* __restrict__ w_qkv,
                                                   const float* __restrict__ w_proj,
                                                   float* __restrict__ ws) {
    const int tid = threadIdx.x;
    const int bid = blockIdx.x;        // 512 blocks
    if (tid < 128) {
        if (bid < 384) {
            unsigned short* wqt = (unsigned short*)(ws + WQT_F_OFF);
            wqt[bid * 128 + tid] = f2bf(w_qkv[(size_t)tid * 384 + bid]);
        } else {
            int j = bid - 384;
            unsigned short* wpt = (unsigned short*)(ws + WT_F_OFF);
            wpt[j * 128 + tid] = f2bf(w_proj[(size_t)tid * 128 + j]);
        }
    }
    int c = bid >> 2, qtr = bid & 3;   // fixed quarter partition (deterministic)
    const float4* xp = (const float4*)(x + (size_t)c * HWZ + qtr * 8192);
    float s = 0.f, ss = 0.f;
#pragma unroll
    for (int i = 0; i < 4; i++) {
        float4 v = xp[tid + i * 512];
        s  += v.x + v.y + v.z + v.w;
        ss += v.x*v.x + v.y*v.y + v.z*v.z + v.w*v.w;
    }
    for (int off = 32; off; off >>= 1) {
        s  += __shfl_down(s, off);
        ss += __shfl_down(ss, off);
    }
    __shared__ float red[16];
    int lane = tid & 63, wid = tid >> 6;
    if (lane == 0) { red[wid] = s; red[8 + wid] = ss; }
    __syncthreads();
    if (tid == 0) {
        float S = 0.f, SS = 0.f;
        for (int w = 0; w < 8; w++) { S += red[w]; SS += red[8 + w]; }
        ws[c * 4 + qtr] = S;
        ws[512 + c * 4 + qtr] = SS;
    }
}

// ---------------- QKV GEMM via bf16 MFMA ----------------
// 1024 blocks x 256 threads (32 positions, 4 waves = 2 ptiles x 2 j-halves):
// 4 blocks/CU -> staggered block phases pipeline HBM staging vs MFMA vs stores.
__global__ __launch_bounds__(256, 4) void qkv_kernel(const float* __restrict__ x,
                                                     const float* __restrict__ b_qkv,
                                                     float* __restrict__ ws) {
    __shared__ unsigned short xs[32 * 128];    // 8 KB: [p][c] bf16, swizzled by p&15
    const int tid = threadIdx.x;
    const int p0 = blockIdx.x * 32;

    // staging: thread = (cgrp, pgrp); 4 rows x 4 positions, vectorized 8B LDS writes
    {
        const int pgrp = tid & 7;         // p = pgrp*4 .. +3  (32 positions)
        const int c0   = (tid >> 3) * 4;  // c = c0 .. c0+3   (32 c-groups)
        float mus[4], rss[4];
#pragma unroll
        for (int ci = 0; ci < 4; ci++) {
            float4 sp = *(const float4*)(ws + (c0 + ci) * 4);
            float4 sq = *(const float4*)(ws + 512 + (c0 + ci) * 4);
            float S  = sp.x + sp.y + sp.z + sp.w;
            float SS = sq.x + sq.y + sq.z + sq.w;
            float mu = S * (1.0f / HWZ);
            float var = SS * (1.0f / HWZ) - mu * mu;
            mus[ci] = mu;
            rss[ci] = rsqrtf(var + 1e-5f);
        }
        unsigned short vals[4][4];        // [ci][pi]
#pragma unroll
        for (int ci = 0; ci < 4; ci++) {
            float4 v = *(const float4*)(x + (size_t)(c0 + ci) * HWZ + p0 + pgrp * 4);
            vals[ci][0] = f2bf((v.x - mus[ci]) * rss[ci]);
            vals[ci][1] = f2bf((v.y - mus[ci]) * rss[ci]);
            vals[ci][2] = f2bf((v.z - mus[ci]) * rss[ci]);
            vals[ci][3] = f2bf((v.w - mus[ci]) * rss[ci]);
        }
        const int c8 = c0 >> 3, cl = c0 & 7;
#pragma unroll
        for (int pi = 0; pi < 4; pi++) {
            int p = pgrp * 4 + pi;
            u16x4 o = {vals[0][pi], vals[1][pi], vals[2][pi], vals[3][pi]};
            *(u16x4*)(xs + p * 128 + ((c8 ^ (p & 15)) << 3) + cl) = o;
        }
    }
    __syncthreads();

    const int wv   = tid >> 6;        // 0..3
    const int lane = tid & 63;
    const int col  = lane & 15;
    const int kgrp = lane >> 4;
    const int ptile = wv & 1;         // 2 p-tiles of 16
    const int jq    = wv >> 1;        // 2 j-halves
    const unsigned short* arow = xs + (ptile * 16 + col) * 128;
    const int arow15 = (ptile * 16 + col) & 15;

    u16x8 a[4];
#pragma unroll
    for (int ks = 0; ks < 4; ks++) {
        a[ks] = *(const u16x8*)(arow + (((ks * 4 + kgrp) ^ arow15) << 3));
    }
    __syncthreads();   // fragment reads done -> xs front reusable as transpose scratch

    const unsigned short* wqt = (const unsigned short*)(ws + WQT_F_OFF);
    unsigned short* qkvb = (unsigned short*)(ws + QKV_F_OFF);
    // wave-private scratch: 16 rows x stride 20 u16 (640B/wave; conflict-free)
    unsigned short* vsc = xs + wv * 320;
    const int rp_ = lane & 15, rdseg = lane >> 4;

    for (int chunk = 0; chunk < 3; chunk++) {
        float scale = (chunk == 0) ? 0.25f : 1.0f;
#pragma unroll
        for (int jt = 0; jt < 4; jt++) {
            int jl = jq * 64 + jt * 16 + col;
            const unsigned short* brow = wqt + (size_t)(chunk * 128 + jl) * 128;
            f32x4 acc = {0.f, 0.f, 0.f, 0.f};
#pragma unroll
            for (int ks = 0; ks < 4; ks++) {
                u16x8 b = *(const u16x8*)(brow + ((ks * 4 + kgrp) << 3));
                acc = __builtin_amdgcn_mfma_f32_16x16x32_bf16(
                        __builtin_bit_cast(bf16x8, a[ks]),
                        __builtin_bit_cast(bf16x8, b), acc, 0, 0, 0);
            }
            int head = jq * 4 + jt;
            float bias = b_qkv[chunk * 128 + head * 16 + col];
            if (chunk == 2) {
                // V transposed global [head][d][p]: direct packed 8B store
                unsigned short* vt = qkvb + 2 * (size_t)REGSZ
                                   + ((size_t)(head * 16 + col)) * HWZ
                                   + p0 + ptile * 16 + kgrp * 4;
                u16x4 o;
#pragma unroll
                for (int i = 0; i < 4; i++) o[i] = f2bf(acc[i] + bias);
                *(u16x4*)vt = o;
            } else {
                // Q/K: transpose via wave-private LDS -> one dense 8B store per lane
#pragma unroll
                for (int i = 0; i < 4; i++) {
                    vsc[(kgrp * 4 + i) * 20 + col] = f2bf((acc[i] + bias) * scale);
                }
                asm volatile("s_waitcnt lgkmcnt(0)" ::: "memory");
                u16x4 vv = *(const u16x4*)(vsc + rp_ * 20 + rdseg * 4);
                unsigned short* dst = qkvb + (size_t)chunk * REGSZ + (size_t)head * HEADSZ
                                    + (size_t)(p0 + ptile * 16 + rp_) * 16 + rdseg * 4;
                *(u16x4*)dst = vv;
            }
        }
    }
}

// ---------------- fused NATTEN attention (MFMA) + output projection ----------------
// block: 512 thr = 8 waves = 8 heads; TWO 16-query tiles, sequential (unroll 1),
// __launch_bounds__(512,4): 2 blocks/CU.
__global__ __launch_bounds__(512, 4) void attnproj_kernel(const float* __restrict__ rpb,
                                                          const float* __restrict__ b_proj,
                                                          float* __restrict__ ws,
                                                          float* __restrict__ out) {
    __shared__ unsigned short aol[32 * 128];   // 8 KB attention-out bf16
    __shared__ float rpb_s[8 * 128];           // 4 KB bias tables
    const int tid = threadIdx.x;

    // XCD-aware bijective swizzle (1024 % 8 == 0)
    const int bid = blockIdx.x;
    const int blk = (bid & 7) * 128 + (bid >> 3);

    for (int i = tid; i < 1024; i += 512) {
        int hh = i >> 7, e = i & 127;
        rpb_s[i] = (e < 125) ? rpb[hh * 125 + e] : 0.f;
    }
    __syncthreads();

    const int p0 = blk * 32;          // 32 positions, all within one h-row
    const int h0 = p0 >> 9;
    const int w0 = (p0 >> 3) & 63;    // tiles at w0 and w0+2
    const int wv = tid >> 6, lane = tid & 63;
    const int head = wv;
    const int g = lane >> 4;          // row-group
    const int qcol = lane & 15;       // query within tile; also key/d row for A loads
    const int lw = qcol >> 3, qz = qcol & 7;
    const int z = qz;

    // ANCHORED h window (shared by both tiles)
    const int sh = min(max(h0 - 1, 0), 61);
    const int dh = sh - h0 + 2;
    const int sz = min(max(z - 1, 0), 5);
    unsigned zmask = 0;
#pragma unroll
    for (int zp = 0; zp < 8; zp++) {
        if (zp >= sz && zp <= sz + 2) zmask |= 1u << zp;
    }

    const unsigned short* qkvb = (const unsigned short*)(ws + QKV_F_OFF);
    const unsigned short* qbase = qkvb + (size_t)head * HEADSZ;
    const unsigned short* kbase = qkvb + (size_t)REGSZ + (size_t)head * HEADSZ;
    const unsigned short* vtb  = qkvb + 2 * (size_t)REGSZ + (size_t)(head * 16) * HWZ;
    const float* bt = rpb_s + head * 128;

    const int iwlA = qcol >> 3, zpA = qcol & 7;    // logits A-row decode
    const int iwlV = g >> 1,   zp0V = (g & 1) * 4; // PV A k-decode

#pragma unroll 1
    for (int t = 0; t < 2; t++) {
        const int pt = p0 + t * 16;
        const int w0t = w0 + t * 2;
        const int w = w0t + lw;
        const int sw = min(max(w - 1, 0), 61);
        unsigned wmask = 0;
#pragma unroll
        for (int iw = 0; iw < 4; iw++) {
            int W = w0t - 1 + iw;
            if (W >= sw && W <= sw + 2) wmask |= 1u << iw;
        }
        int Wc[4];
#pragma unroll
        for (int iw = 0; iw < 4; iw++) Wc[iw] = min(max(w0t - 1 + iw, 0), 63);

        // ---- prefetch: Q, all K fragments, all V fragments ----
        s16x4 bq = *(const s16x4*)(qbase + (size_t)(pt + qcol) * 16 + g * 4);
        s16x4 ak[6], av[6];
#pragma unroll
        for (int mt = 0; mt < 6; mt++) {
            int iwA = (mt & 1) * 2 + iwlA;
            int pkK = (sh + (mt >> 1)) * 512 + Wc[iwA] * 8 + zpA;
            ak[mt] = *(const s16x4*)(kbase + (size_t)pkK * 16 + g * 4);
            int iwV = (mt & 1) * 2 + iwlV;
            int pkV = (sh + (mt >> 1)) * 512 + Wc[iwV] * 8 + zp0V;
            av[mt] = *(const s16x4*)(vtb + (size_t)qcol * HWZ + pkV);
        }

        // ---- logits: 6 independent Mtiles ----
        f32x4 acc[6];
#pragma unroll
        for (int mt = 0; mt < 6; mt++) {
            f32x4 zero = {0.f, 0.f, 0.f, 0.f};
            acc[mt] = __builtin_amdgcn_mfma_f32_16x16x16bf16_1k(ak[mt], bq, zero, 0, 0, 0);
        }

        // ---- mask + bias + softmax (no max pass; exp in place) ----
        float ssum = 0.f;
#pragma unroll
        for (int mt = 0; mt < 6; mt++) {
            int ih = mt >> 1;
#pragma unroll
            for (int r = 0; r < 4; r++) {
                int krow = g * 4 + r;
                int iw = (mt & 1) * 2 + (krow >> 3);
                int zp = krow & 7;
                int ok = ((wmask >> iw) & 1) & ((zmask >> zp) & 1);
                int idx = (dh + ih) * 25 + (iw + 1 - lw) * 5 + (zp - z + 2);
                idx = ok ? idx : 62;
                float lg = ok ? (acc[mt][r] + bt[idx]) : -1e30f;
                float pexp = __expf(lg);
                acc[mt][r] = pexp;
                ssum += pexp;
            }
        }
        ssum += __shfl_xor(ssum, 16);
        ssum += __shfl_xor(ssum, 32);
        float inv = 1.f / ssum;

        // P -> bf16 fragments (B operand layout == accumulator layout)
        s16x4 pb[6];
#pragma unroll
        for (int mt = 0; mt < 6; mt++)
#pragma unroll
            for (int r = 0; r < 4; r++)
                pb[mt][r] = (short)f2bf(acc[mt][r]);

        // ---- PV: out(16d x 16q) = V^T @ P, two independent chains ----
        f32x4 o0 = {0.f, 0.f, 0.f, 0.f}, o1 = {0.f, 0.f, 0.f, 0.f};
        o0 = __builtin_amdgcn_mfma_f32_16x16x16bf16_1k(av[0], pb[0], o0, 0, 0, 0);
        o1 = __builtin_amdgcn_mfma_f32_16x16x16bf16_1k(av[1], pb[1], o1, 0, 0, 0);
        o0 = __builtin_amdgcn_mfma_f32_16x16x16bf16_1k(av[2], pb[2], o0, 0, 0, 0);
        o1 = __builtin_amdgcn_mfma_f32_16x16x16bf16_1k(av[3], pb[3], o1, 0, 0, 0);
        o0 = __builtin_amdgcn_mfma_f32_16x16x16bf16_1k(av[4], pb[4], o0, 0, 0, 0);
        o1 = __builtin_amdgcn_mfma_f32_16x16x16bf16_1k(av[5], pb[5], o1, 0, 0, 0);
        f32x4 oacc = o0 + o1;

        // write to aol[q + t*16][c], 16B groups swizzled by q&15
#pragma unroll
        for (int r = 0; r < 4; r++) {
            int c = head * 16 + g * 4 + r;
            aol[(t * 16 + qcol) * 128 + (((c >> 3) ^ qcol) << 3) + (c & 7)] = f2bf(oacc[r] * inv);
        }
    }

    // proj B-fragments: load BEFORE the barrier (independent of aol)
    const unsigned short* wpt = (const unsigned short*)(ws + WT_F_OFF);
    const int j = wv * 16 + qcol;
    const unsigned short* bp = wpt + j * 128;
    u16x8 b0 = *(const u16x8*)(bp + ((0 * 4 + g) << 3));
    u16x8 b1 = *(const u16x8*)(bp + ((1 * 4 + g) << 3));
    u16x8 b2 = *(const u16x8*)(bp + ((2 * 4 + g) << 3));
    u16x8 b3 = *(const u16x8*)(bp + ((3 * 4 + g) << 3));
    float bias = b_proj[j];
    __syncthreads();

    // ---- proj GEMM: both position-tiles against the same B fragments ----
#pragma unroll
    for (int t = 0; t < 2; t++) {
        const unsigned short* ap = aol + (t * 16 + qcol) * 128;
        u16x8 a[4];
#pragma unroll
        for (int ks = 0; ks < 4; ks++) {
            a[ks] = *(const u16x8*)(ap + (((ks * 4 + g) ^ qcol) << 3));
        }
        f32x4 p0a = {0.f, 0.f, 0.f, 0.f}, p1a = {0.f, 0.f, 0.f, 0.f};
        p0a = __builtin_amdgcn_mfma_f32_16x16x32_bf16(__builtin_bit_cast(bf16x8, a[0]),
                __builtin_bit_cast(bf16x8, b0), p0a, 0, 0, 0);
        p1a = __builtin_amdgcn_mfma_f32_16x16x32_bf16(__builtin_bit_cast(bf16x8, a[1]),
                __builtin_bit_cast(bf16x8, b1), p1a, 0, 0, 0);
        p0a = __builtin_amdgcn_mfma_f32_16x16x32_bf16(__builtin_bit_cast(bf16x8, a[2]),
                __builtin_bit_cast(bf16x8, b2), p0a, 0, 0, 0);
        p1a = __builtin_amdgcn_mfma_f32_16x16x32_bf16(__builtin_bit_cast(bf16x8, a[3]),
                __builtin_bit_cast(bf16x8, b3), p1a, 0, 0, 0);
        f32x4 pacc = p0a + p1a;

        float4 o4;
        o4.x = pacc[0] + bias; o4.y = pacc[1] + bias;
        o4.z = pacc[2] + bias; o4.w = pacc[3] + bias;
        *(float4*)(out + (size_t)j * HWZ + p0 + t * 16 + g * 4) = o4;
    }
}

extern "C" void kernel_launch(void* const* d_in, const int* in_sizes, int n_in,
                              void* d_out, int out_size, void* d_ws, size_t ws_size,
                              hipStream_t stream) {
    const float* x      = (const float*)d_in[0];
    const float* w_qkv  = (const float*)d_in[1];
    const float* b_qkv  = (const float*)d_in[2];
    const float* rpb    = (const float*)d_in[3];
    const float* w_proj = (const float*)d_in[4];
    const float* b_proj = (const float*)d_in[5];
    float* out = (float*)d_out;
    float* ws  = (float*)d_ws;

    prep_kernel<<<512, 512, 0, stream>>>(x, w_qkv, w_proj, ws);
    qkv_kernel<<<1024, 256, 0, stream>>>(x, b_qkv, ws);
    attnproj_kernel<<<1024, 512, 0, stream>>>(rpb, b_proj, ws, out);
}